// Round 6
// baseline (146.121 us; speedup 1.0000x reference)
//
#include <hip/hip_runtime.h>

#define B_   64
#define N_   2304
#define J_   32
#define L_   16
#define EPS_ 1e-7f
#define BG   4       // batches per block
#define NSPL 16      // n-splits
#define NSL  144     // n per split
#define NTHR 1024
#define NT   18      // tiles (NSL/8)
#define STR  20      // sred per-slot stride in floats (80 B, 16B-aligned, conflict-avoiding)

// d_ws layout (floats):
//   Ws [N*J*L] | xs_g [B*N] | p0 [B*NSPL*512] | s0 [B*512] | s1 [B*512] | s2 [B*512] | ctr (int)
// s1, s2, ctr form the zero-region cleared by prep each call (prep -> iters is a kernel boundary).

// ---- prep: Ws = sum_k W; xs_g = sum_i x; zero s1/s2/ctr ----
__global__ __launch_bounds__(256) void prep_kernel(const float* __restrict__ x,
                                                   const float* __restrict__ W,
                                                   float* __restrict__ Ws,
                                                   float* __restrict__ xs_g,
                                                   float* __restrict__ zr) {
    const int o = blockIdx.x * 256 + threadIdx.x;
    if (o < 2 * B_ * 512 + 1) zr[o] = 0.f;          // s1, s2, ctr(=0 bits)
    const int NW4 = N_ * J_ * L_ / 4;
    if (o < NW4) {
        const int n = o >> 7, r = o & 127;          // r = j*4 + l4
        const float4* base = (const float4*)W + (size_t)n * 1024 + (r >> 2) * 32 + (r & 3);
        float4 s = make_float4(0.f, 0.f, 0.f, 0.f);
#pragma unroll
        for (int k = 0; k < 8; ++k) {
            float4 t = base[k * 4];
            s.x += t.x; s.y += t.y; s.z += t.z; s.w += t.w;
        }
        ((float4*)Ws)[o] = s;
    } else {
        const int q = o - NW4;                      // 0 .. B*N-1
        if (q < B_ * N_) {
            const float4* p4 = (const float4*)(x + (size_t)q * 8);
            float4 a = p4[0], c = p4[1];
            xs_g[q] = a.x + a.y + a.z + a.w + c.x + c.y + c.z + c.w;
        }
    }
}

// ---- one routing iteration. Block = (bg, sp): 4 batches x 144 n. ----
// T=0: uniform weights -> p0 partials (exclusive writes, no zero needed).
// T=1: u = squash(sum_sp p0); sp==0 blocks also store raw s0; tail atomicAdd -> s1.
// T=2: u = squash(s0) + squash(s1); tail atomicAdd -> s2; last block squashes s2 -> out.
template<int T>
__global__ __launch_bounds__(NTHR) void iter_kernel(const float* __restrict__ Ws,
                                                    const float* __restrict__ xs_g,
                                                    const float* __restrict__ p0,
                                                    float* __restrict__ s0g,
                                                    float* __restrict__ s1g,
                                                    float* __restrict__ s2g,
                                                    int* __restrict__ ctr,
                                                    float* __restrict__ pout,
                                                    float* __restrict__ out) {
    __shared__ float xs_lds[BG * NSL];         // 2.3 KB
    __shared__ float u_lds[BG * 544];          // 8.7 KB, [b][j*17+l] padded (bank-bijective)
    __shared__ float sred[512 * STR];          // 40 KB
    __shared__ int lastflag;

    const int tid = threadIdx.x;
    const int sp  = blockIdx.x & 15;
    const int bg  = blockIdx.x >> 4;
    const int bb  = bg * BG;
    const int nb  = sp * NSL;

    if (tid < BG * NSL) {
        const int b4f = tid / NSL, nlf = tid - b4f * NSL;
        xs_lds[tid] = xs_g[(size_t)(bb + b4f) * N_ + nb + nlf];
    }

    if constexpr (T == 1) {
        // u from p0 slice-sum (redundant per sp-block); sp==0 also emits raw s0
        for (int q = tid; q < BG * 512; q += NTHR) {
            const int ob = q >> 9, jl = q & 511;
            const float* pp = p0 + ((size_t)(bb + ob) * NSPL) * 512 + jl;
            float s = 0.f;
#pragma unroll
            for (int s2i = 0; s2i < NSPL; ++s2i) s += pp[s2i * 512];
            if (sp == 0) s0g[(bb + ob) * 512 + jl] = s;
            float sq = s * s;
#pragma unroll
            for (int off = 1; off <= 8; off <<= 1) sq += __shfl_xor(sq, off);
            u_lds[ob * 544 + (jl >> 4) * 17 + (jl & 15)] =
                s * (sq / (1.f + sq) / sqrtf(sq + EPS_));
        }
    } else if constexpr (T == 2) {
        // u = squash(s0) + squash(s1) from direct reads (cheap)
        for (int q = tid; q < BG * 512; q += NTHR) {
            const int ob = q >> 9, jl = q & 511;
            const int g = (bb + ob) * 512 + jl;
            float s = s0g[g];
            float sq = s * s;
#pragma unroll
            for (int off = 1; off <= 8; off <<= 1) sq += __shfl_xor(sq, off);
            float u = s * (sq / (1.f + sq) / sqrtf(sq + EPS_));
            float s1 = s1g[g];
            float sq1 = s1 * s1;
#pragma unroll
            for (int off = 1; off <= 8; off <<= 1) sq1 += __shfl_xor(sq1, off);
            u += s1 * (sq1 / (1.f + sq1) / sqrtf(sq1 + EPS_));
            u_lds[ob * 544 + (jl >> 4) * 17 + (jl & 15)] = u;
        }
    }
    __syncthreads();

    const int nl8 = tid >> 7;                  // 0..7 n-lane
    const int b4  = (tid >> 5) & 3;            // batch within group
    const int j   = tid & 31;                  // capsule

    float u4[16];
    if constexpr (T > 0) {
#pragma unroll
        for (int l = 0; l < 16; ++l) u4[l] = u_lds[b4 * 544 + j * 17 + l];
    }

    float acc[16];
#pragma unroll
    for (int l = 0; l < 16; ++l) acc[l] = 0.f;

    const float* wbase = Ws + (size_t)nb * 512 + j * 16;
    const float* xbase = xs_lds + b4 * NSL;

    for (int tile = 0; tile < NT; ++tile) {
        const int nl = tile * 8 + nl8;
        const float4* wr = (const float4*)(wbase + (size_t)nl * 512);
        float4 w0 = wr[0], w1 = wr[1], w2 = wr[2], w3 = wr[3];
        const float xsv = xbase[nl];
        float wgt;
        if constexpr (T == 0) {
            wgt = xsv * (1.f / 32.f);
        } else {
            float lg = w0.x*u4[0]  + w0.y*u4[1]  + w0.z*u4[2]  + w0.w*u4[3]
                     + w1.x*u4[4]  + w1.y*u4[5]  + w1.z*u4[6]  + w1.w*u4[7]
                     + w2.x*u4[8]  + w2.y*u4[9]  + w2.z*u4[10] + w2.w*u4[11]
                     + w3.x*u4[12] + w3.y*u4[13] + w3.z*u4[14] + w3.w*u4[15];
            lg *= xsv;
            float e = __expf(lg);              // |lg| < ~25: no max-pass needed
            float ss = e;
#pragma unroll
            for (int off = 1; off <= 16; off <<= 1) ss += __shfl_xor(ss, off);
            wgt = (e / ss) * xsv;
        }
        acc[0]  += wgt*w0.x; acc[1]  += wgt*w0.y; acc[2]  += wgt*w0.z; acc[3]  += wgt*w0.w;
        acc[4]  += wgt*w1.x; acc[5]  += wgt*w1.y; acc[6]  += wgt*w1.z; acc[7]  += wgt*w1.w;
        acc[8]  += wgt*w2.x; acc[9]  += wgt*w2.y; acc[10] += wgt*w2.z; acc[11] += wgt*w2.w;
        acc[12] += wgt*w3.x; acc[13] += wgt*w3.y; acc[14] += wgt*w3.z; acc[15] += wgt*w3.w;
    }

    // ---- two-stage n-lane reduction (upper half stores, lower half adds) ----
    if (nl8 >= 4) {
        float* sr = sred + (size_t)(tid - 512) * STR;
        ((float4*)sr)[0] = make_float4(acc[0],  acc[1],  acc[2],  acc[3]);
        ((float4*)sr)[1] = make_float4(acc[4],  acc[5],  acc[6],  acc[7]);
        ((float4*)sr)[2] = make_float4(acc[8],  acc[9],  acc[10], acc[11]);
        ((float4*)sr)[3] = make_float4(acc[12], acc[13], acc[14], acc[15]);
    }
    __syncthreads();
    if (nl8 < 4) {
        float* sr = sred + (size_t)tid * STR;
#pragma unroll
        for (int d = 0; d < 4; ++d) {
            float4 t = ((float4*)sr)[d];
            t.x += acc[d*4+0]; t.y += acc[d*4+1]; t.z += acc[d*4+2]; t.w += acc[d*4+3];
            ((float4*)sr)[d] = t;
        }
    }
    __syncthreads();

    // ---- tail: reduce 4 slots; write p0 partials (T=0) or atomic s1/s2 ----
    for (int q = tid; q < BG * 512; q += NTHR) {
        const int ob = q >> 9, jl = q & 511;
        const int oj = jl >> 4, ol = jl & 15;
        float s = 0.f;
#pragma unroll
        for (int nl = 0; nl < 4; ++nl)
            s += sred[(size_t)(nl * 128 + ob * 32 + oj) * STR + ol];
        if constexpr (T == 0)
            pout[((size_t)(bb + ob) * NSPL + sp) * 512 + jl] = s;
        else if constexpr (T == 1)
            unsafeAtomicAdd(&s1g[(bb + ob) * 512 + jl], s);
        else
            unsafeAtomicAdd(&s2g[(bb + ob) * 512 + jl], s);
    }

    if constexpr (T == 2) {
        // ---- last-block: squash(s2) -> out (single check, no spinning) ----
        __threadfence();
        __syncthreads();
        if (tid == 0) {
            int old = __hip_atomic_fetch_add(ctr, 1, __ATOMIC_ACQ_REL,
                                             __HIP_MEMORY_SCOPE_AGENT);
            lastflag = (old == 255) ? 1 : 0;
        }
        __syncthreads();
        if (lastflag) {
            __threadfence();
            for (int r = tid; r < B_ * J_; r += NTHR) {
                const int b = r >> 5, jj = r & 31;
                const float4* s4 = (const float4*)(s2g + b * 512 + jj * 16);
                float4 a0 = s4[0], a1 = s4[1], a2 = s4[2], a3 = s4[3];
                float sq = a0.x*a0.x + a0.y*a0.y + a0.z*a0.z + a0.w*a0.w
                         + a1.x*a1.x + a1.y*a1.y + a1.z*a1.z + a1.w*a1.w
                         + a2.x*a2.x + a2.y*a2.y + a2.z*a2.z + a2.w*a2.w
                         + a3.x*a3.x + a3.y*a3.y + a3.z*a3.z + a3.w*a3.w;
                const float sc = sq / (1.f + sq) / sqrtf(sq + EPS_);
                float4* o4 = (float4*)(out + b * 512 + jj * 16);
                o4[0] = make_float4(a0.x*sc, a0.y*sc, a0.z*sc, a0.w*sc);
                o4[1] = make_float4(a1.x*sc, a1.y*sc, a1.z*sc, a1.w*sc);
                o4[2] = make_float4(a2.x*sc, a2.y*sc, a2.z*sc, a2.w*sc);
                o4[3] = make_float4(a3.x*sc, a3.y*sc, a3.z*sc, a3.w*sc);
            }
        }
    }
}

extern "C" void kernel_launch(void* const* d_in, const int* in_sizes, int n_in,
                              void* d_out, int out_size, void* d_ws, size_t ws_size,
                              hipStream_t stream) {
    const float* x = (const float*)d_in[0];   // [B, N, 8]
    const float* W = (const float*)d_in[1];   // [N, J, 8, L]
    float* out = (float*)d_out;               // [B, J, L]

    float* Ws  = (float*)d_ws;                         // N*J*L
    float* xsg = Ws  + (size_t)N_ * J_ * L_;           // B*N
    float* p0  = xsg + (size_t)B_ * N_;                // B*NSPL*512
    float* s0  = p0  + (size_t)B_ * NSPL * 512;        // B*512
    float* s1  = s0  + (size_t)B_ * 512;               // B*512  (zero-region start)
    float* s2  = s1  + (size_t)B_ * 512;               // B*512
    int*   ctr = (int*)(s2 + (size_t)B_ * 512);        // 1 int

    prep_kernel<<<1728, 256, 0, stream>>>(x, W, Ws, xsg, s1);
    iter_kernel<0><<<256, NTHR, 0, stream>>>(Ws, xsg, nullptr, nullptr, nullptr,
                                             nullptr, nullptr, p0, nullptr);
    iter_kernel<1><<<256, NTHR, 0, stream>>>(Ws, xsg, p0, s0, s1,
                                             nullptr, nullptr, nullptr, nullptr);
    iter_kernel<2><<<256, NTHR, 0, stream>>>(Ws, xsg, nullptr, s0, s1,
                                             s2, ctr, nullptr, out);
}

// Round 7
// 99.125 us; speedup vs baseline: 1.4741x; 1.4741x over previous
//
#include <hip/hip_runtime.h>

#define B_   64
#define N_   2304
#define J_   32
#define L_   16
#define EPS_ 1e-7f
#define BG   4       // batches per block
#define NSPL 16      // n-splits
#define NSL  144     // n per split
#define NTHR 1024
#define NT   18      // tiles (NSL/8)
#define STR  20      // sred per-slot stride in floats (80 B, 16B-aligned, conflict-avoiding)

// d_ws layout (floats):
//   Ws [N*J*L] | xs_g [B*N] | p0 [B*NSPL*512] | p1 [B*NSPL*512] | s2 [B*512] | ctr (int)
// s2 + ctr are zeroed by prep each call (prep -> iters is a kernel boundary).

// ---- prep: Ws = sum_k W; xs_g = sum_i x; zero s2/ctr ----
__global__ __launch_bounds__(256) void prep_kernel(const float* __restrict__ x,
                                                   const float* __restrict__ W,
                                                   float* __restrict__ Ws,
                                                   float* __restrict__ xs_g,
                                                   float* __restrict__ zr) {
    const int o = blockIdx.x * 256 + threadIdx.x;
    if (o < B_ * 512 + 1) zr[o] = 0.f;              // s2 then ctr(=0 bits)
    const int NW4 = N_ * J_ * L_ / 4;               // 294912 float4 outputs
    if (o < NW4) {
        const int n = o >> 7, r = o & 127;          // r = j*4 + l4
        const float4* base = (const float4*)W + (size_t)n * 1024 + (r >> 2) * 32 + (r & 3);
        float4 s = make_float4(0.f, 0.f, 0.f, 0.f);
#pragma unroll
        for (int k = 0; k < 8; ++k) {
            float4 t = base[k * 4];
            s.x += t.x; s.y += t.y; s.z += t.z; s.w += t.w;
        }
        ((float4*)Ws)[o] = s;
    } else {
        const int q = o - NW4;                      // 0 .. B*N-1
        if (q < B_ * N_) {
            const float4* p4 = (const float4*)(x + (size_t)q * 8);
            float4 a = p4[0], c = p4[1];
            xs_g[q] = a.x + a.y + a.z + a.w + c.x + c.y + c.z + c.w;
        }
    }
}

// ---- one routing iteration. Block = (bg, sp): 4 batches x 144 n. ----
// T=0: uniform weights -> p0 partials (exclusive writes).
// T=1: u = squash(sum_sp p0) -> p1 partials.
// T=2: u = squash(sum p0) + squash(sum p1); tail atomics -> s2; last block squashes -> out.
template<int T>
__global__ __launch_bounds__(NTHR) void iter_kernel(const float* __restrict__ Ws,
                                                    const float* __restrict__ xs_g,
                                                    const float* __restrict__ pA,
                                                    const float* __restrict__ pB,
                                                    float* __restrict__ pout,
                                                    float* __restrict__ s2g,
                                                    int* __restrict__ ctr,
                                                    float* __restrict__ out) {
    __shared__ float xs_lds[BG * NSL];         // 2.3 KB
    __shared__ float u_lds[BG * 544];          // 8.7 KB, [b][j*17+l] padded (bank-bijective)
    __shared__ float sred[512 * STR];          // 40 KB
    __shared__ int lastflag;

    const int tid = threadIdx.x;
    const int sp  = blockIdx.x & 15;
    const int bg  = blockIdx.x >> 4;
    const int bb  = bg * BG;
    const int nb  = sp * NSL;

    if (tid < BG * NSL) {
        const int b4f = tid / NSL, nlf = tid - b4f * NSL;
        xs_lds[tid] = xs_g[(size_t)(bb + b4f) * N_ + nb + nlf];
    }

    if constexpr (T > 0) {
        // u from redundant slice-sum + squash of previous partials (L2/L3-resident)
        for (int q = tid; q < BG * 512; q += NTHR) {
            const int ob = q >> 9, jl = q & 511;
            const float* pp = pA + ((size_t)(bb + ob) * NSPL) * 512 + jl;
            float s = 0.f;
#pragma unroll
            for (int s2i = 0; s2i < NSPL; ++s2i) s += pp[s2i * 512];
            float sq = s * s;
#pragma unroll
            for (int off = 1; off <= 8; off <<= 1) sq += __shfl_xor(sq, off);
            float u = s * (sq / (1.f + sq) / sqrtf(sq + EPS_));
            if constexpr (T == 2) {
                const float* pq = pB + ((size_t)(bb + ob) * NSPL) * 512 + jl;
                float s1 = 0.f;
#pragma unroll
                for (int s2i = 0; s2i < NSPL; ++s2i) s1 += pq[s2i * 512];
                float sq1 = s1 * s1;
#pragma unroll
                for (int off = 1; off <= 8; off <<= 1) sq1 += __shfl_xor(sq1, off);
                u += s1 * (sq1 / (1.f + sq1) / sqrtf(sq1 + EPS_));
            }
            u_lds[ob * 544 + (jl >> 4) * 17 + (jl & 15)] = u;
        }
    }
    __syncthreads();

    const int nl8 = tid >> 7;                  // 0..7 n-lane
    const int b4  = (tid >> 5) & 3;            // batch within group
    const int j   = tid & 31;                  // capsule

    float u4[16];
    if constexpr (T > 0) {
#pragma unroll
        for (int l = 0; l < 16; ++l) u4[l] = u_lds[b4 * 544 + j * 17 + l];
    }

    float acc[16];
#pragma unroll
    for (int l = 0; l < 16; ++l) acc[l] = 0.f;

    const float* wbase = Ws + (size_t)nb * 512 + j * 16;
    const float* xbase = xs_lds + b4 * NSL;

    for (int tile = 0; tile < NT; ++tile) {
        const int nl = tile * 8 + nl8;
        const float4* wr = (const float4*)(wbase + (size_t)nl * 512);
        float4 w0 = wr[0], w1 = wr[1], w2 = wr[2], w3 = wr[3];
        const float xsv = xbase[nl];
        float wgt;
        if constexpr (T == 0) {
            wgt = xsv * (1.f / 32.f);
        } else {
            float lg = w0.x*u4[0]  + w0.y*u4[1]  + w0.z*u4[2]  + w0.w*u4[3]
                     + w1.x*u4[4]  + w1.y*u4[5]  + w1.z*u4[6]  + w1.w*u4[7]
                     + w2.x*u4[8]  + w2.y*u4[9]  + w2.z*u4[10] + w2.w*u4[11]
                     + w3.x*u4[12] + w3.y*u4[13] + w3.z*u4[14] + w3.w*u4[15];
            lg *= xsv;
            float e = __expf(lg);              // |lg| < ~25: no max-pass needed
            float ss = e;
#pragma unroll
            for (int off = 1; off <= 16; off <<= 1) ss += __shfl_xor(ss, off);
            wgt = (e / ss) * xsv;
        }
        acc[0]  += wgt*w0.x; acc[1]  += wgt*w0.y; acc[2]  += wgt*w0.z; acc[3]  += wgt*w0.w;
        acc[4]  += wgt*w1.x; acc[5]  += wgt*w1.y; acc[6]  += wgt*w1.z; acc[7]  += wgt*w1.w;
        acc[8]  += wgt*w2.x; acc[9]  += wgt*w2.y; acc[10] += wgt*w2.z; acc[11] += wgt*w2.w;
        acc[12] += wgt*w3.x; acc[13] += wgt*w3.y; acc[14] += wgt*w3.z; acc[15] += wgt*w3.w;
    }

    // ---- two-stage n-lane reduction (upper half stores, lower half adds) ----
    if (nl8 >= 4) {
        float* sr = sred + (size_t)(tid - 512) * STR;
        ((float4*)sr)[0] = make_float4(acc[0],  acc[1],  acc[2],  acc[3]);
        ((float4*)sr)[1] = make_float4(acc[4],  acc[5],  acc[6],  acc[7]);
        ((float4*)sr)[2] = make_float4(acc[8],  acc[9],  acc[10], acc[11]);
        ((float4*)sr)[3] = make_float4(acc[12], acc[13], acc[14], acc[15]);
    }
    __syncthreads();
    if (nl8 < 4) {
        float* sr = sred + (size_t)tid * STR;
#pragma unroll
        for (int d = 0; d < 4; ++d) {
            float4 t = ((float4*)sr)[d];
            t.x += acc[d*4+0]; t.y += acc[d*4+1]; t.z += acc[d*4+2]; t.w += acc[d*4+3];
            ((float4*)sr)[d] = t;
        }
    }
    __syncthreads();

    // ---- tail: reduce 4 slots; write partials (T<2) or atomic-add s2 (T=2) ----
    for (int q = tid; q < BG * 512; q += NTHR) {
        const int ob = q >> 9, jl = q & 511;
        const int oj = jl >> 4, ol = jl & 15;
        float s = 0.f;
#pragma unroll
        for (int nl = 0; nl < 4; ++nl)
            s += sred[(size_t)(nl * 128 + ob * 32 + oj) * STR + ol];
        if constexpr (T < 2)
            pout[((size_t)(bb + ob) * NSPL + sp) * 512 + jl] = s;
        else
            unsafeAtomicAdd(&s2g[(bb + ob) * 512 + jl], s);
    }

    if constexpr (T == 2) {
        // __syncthreads drains vmcnt(0): this block's s2 atomics are complete
        // at the device-coherent point before the (relaxed) counter RMW below.
        __syncthreads();
        if (tid == 0) {
            int old = __hip_atomic_fetch_add(ctr, 1, __ATOMIC_RELAXED,
                                             __HIP_MEMORY_SCOPE_AGENT);
            lastflag = (old == 255) ? 1 : 0;
        }
        __syncthreads();
        if (lastflag) {
            // last block: all 256 blocks' atomics are at the coherent point.
            // Read s2 with agent-scope atomic loads (no stale L1/L2), squash -> out.
            for (int r = tid; r < B_ * J_; r += NTHR) {
                const int b = r >> 5, jj = r & 31;
                const float* s4 = s2g + b * 512 + jj * 16;
                float v[16];
                float sq = 0.f;
#pragma unroll
                for (int l = 0; l < 16; ++l) {
                    v[l] = __hip_atomic_load(&s4[l], __ATOMIC_RELAXED,
                                             __HIP_MEMORY_SCOPE_AGENT);
                    sq += v[l] * v[l];
                }
                const float sc = sq / (1.f + sq) / sqrtf(sq + EPS_);
                float* o = out + b * 512 + jj * 16;
#pragma unroll
                for (int l = 0; l < 16; ++l) o[l] = v[l] * sc;
            }
        }
    }
}

extern "C" void kernel_launch(void* const* d_in, const int* in_sizes, int n_in,
                              void* d_out, int out_size, void* d_ws, size_t ws_size,
                              hipStream_t stream) {
    const float* x = (const float*)d_in[0];   // [B, N, 8]
    const float* W = (const float*)d_in[1];   // [N, J, 8, L]
    float* out = (float*)d_out;               // [B, J, L]

    float* Ws  = (float*)d_ws;                         // N*J*L
    float* xsg = Ws  + (size_t)N_ * J_ * L_;           // B*N
    float* p0  = xsg + (size_t)B_ * N_;                // B*NSPL*512
    float* p1  = p0  + (size_t)B_ * NSPL * 512;        // B*NSPL*512
    float* s2  = p1  + (size_t)B_ * NSPL * 512;        // B*512 (zeroed by prep)
    int*   ctr = (int*)(s2 + (size_t)B_ * 512);        // 1 int (zeroed by prep)

    prep_kernel<<<1728, 256, 0, stream>>>(x, W, Ws, xsg, s2);
    iter_kernel<0><<<256, NTHR, 0, stream>>>(Ws, xsg, nullptr, nullptr, p0,
                                             nullptr, nullptr, nullptr);
    iter_kernel<1><<<256, NTHR, 0, stream>>>(Ws, xsg, p0, nullptr, p1,
                                             nullptr, nullptr, nullptr);
    iter_kernel<2><<<256, NTHR, 0, stream>>>(Ws, xsg, p0, p1, nullptr,
                                             s2, ctr, out);
}

// Round 8
// 91.305 us; speedup vs baseline: 1.6004x; 1.0856x over previous
//
#include <hip/hip_runtime.h>

#define B_   64
#define N_   2304
#define J_   32
#define L_   16
#define EPS_ 1e-7f
#define BG   4       // batches per block
#define NSPL 32      // n-splits
#define NSL  72      // n per split (NSPL*NSL == N_)
#define NGRID (NSPL * (B_ / BG))   // 512 blocks -> 2 blocks/CU
#define NTHR 1024
#define NT   9       // tiles (NSL/8)
#define STR  20      // sred per-slot stride in floats (80 B, 16B-aligned, conflict-avoiding)

// d_ws layout (floats):
//   Ws [N*J*L] | xs_g [B*N] | p0 [B*NSPL*512] | p1 [B*NSPL*512] | p2 [B*NSPL*512] | s0 [B*512]
// All writes are exclusive; kernel boundaries are the only synchronization.

// ---- prep: Ws = sum_k W; xs_g = sum_i x ----
__global__ __launch_bounds__(256) void prep_kernel(const float* __restrict__ x,
                                                   const float* __restrict__ W,
                                                   float* __restrict__ Ws,
                                                   float* __restrict__ xs_g) {
    const int o = blockIdx.x * 256 + threadIdx.x;
    const int NW4 = N_ * J_ * L_ / 4;               // 294912 float4 outputs
    if (o < NW4) {
        const int n = o >> 7, r = o & 127;          // r = j*4 + l4
        const float4* base = (const float4*)W + (size_t)n * 1024 + (r >> 2) * 32 + (r & 3);
        float4 s = make_float4(0.f, 0.f, 0.f, 0.f);
#pragma unroll
        for (int k = 0; k < 8; ++k) {
            float4 t = base[k * 4];
            s.x += t.x; s.y += t.y; s.z += t.z; s.w += t.w;
        }
        ((float4*)Ws)[o] = s;
    } else {
        const int q = o - NW4;                      // 0 .. B*N-1
        if (q < B_ * N_) {
            const float4* p4 = (const float4*)(x + (size_t)q * 8);
            float4 a = p4[0], c = p4[1];
            xs_g[q] = a.x + a.y + a.z + a.w + c.x + c.y + c.z + c.w;
        }
    }
}

// ---- one routing iteration. Block = (bg, sp): 4 batches x 72 n. Grid 512. ----
// T=0: uniform weights -> p0 (exclusive writes).
// T=1: u = squash(sum_sp p0); sp==0 blocks also store raw s0; -> p1.
// T=2: u = squash(s0) + squash(sum_sp p1); -> p2.
template<int T>
__global__ __launch_bounds__(NTHR) void iter_kernel(const float* __restrict__ Ws,
                                                    const float* __restrict__ xs_g,
                                                    const float* __restrict__ pA,
                                                    float* __restrict__ s0g,
                                                    float* __restrict__ pout) {
    __shared__ float xs_lds[BG * NSL];         // 1.2 KB
    __shared__ float u_lds[BG * 544];          // 8.7 KB, [b][j*17+l] padded (bank-bijective)
    __shared__ float sred[512 * STR];          // 40 KB

    const int tid = threadIdx.x;
    const int sp  = blockIdx.x & (NSPL - 1);
    const int bg  = blockIdx.x >> 5;
    const int bb  = bg * BG;
    const int nb  = sp * NSL;

    if (tid < BG * NSL) {
        const int b4f = tid / NSL, nlf = tid - b4f * NSL;
        xs_lds[tid] = xs_g[(size_t)(bb + b4f) * N_ + nb + nlf];
    }

    if constexpr (T == 1) {
        // u = squash(sum of p0 slices); sp==0 blocks also emit the raw sum s0
        for (int q = tid; q < BG * 512; q += NTHR) {
            const int ob = q >> 9, jl = q & 511;
            const float* pp = pA + ((size_t)(bb + ob) * NSPL) * 512 + jl;
            float s = 0.f;
#pragma unroll
            for (int s2i = 0; s2i < NSPL; ++s2i) s += pp[s2i * 512];
            if (sp == 0) s0g[(bb + ob) * 512 + jl] = s;
            float sq = s * s;
#pragma unroll
            for (int off = 1; off <= 8; off <<= 1) sq += __shfl_xor(sq, off);
            u_lds[ob * 544 + (jl >> 4) * 17 + (jl & 15)] =
                s * (sq / (1.f + sq) / sqrtf(sq + EPS_));
        }
    } else if constexpr (T == 2) {
        // u = squash(s0) + squash(sum of p1 slices)
        for (int q = tid; q < BG * 512; q += NTHR) {
            const int ob = q >> 9, jl = q & 511;
            float s = s0g[(bb + ob) * 512 + jl];
            float sq = s * s;
#pragma unroll
            for (int off = 1; off <= 8; off <<= 1) sq += __shfl_xor(sq, off);
            float u = s * (sq / (1.f + sq) / sqrtf(sq + EPS_));
            const float* pp = pA + ((size_t)(bb + ob) * NSPL) * 512 + jl;
            float s1 = 0.f;
#pragma unroll
            for (int s2i = 0; s2i < NSPL; ++s2i) s1 += pp[s2i * 512];
            float sq1 = s1 * s1;
#pragma unroll
            for (int off = 1; off <= 8; off <<= 1) sq1 += __shfl_xor(sq1, off);
            u += s1 * (sq1 / (1.f + sq1) / sqrtf(sq1 + EPS_));
            u_lds[ob * 544 + (jl >> 4) * 17 + (jl & 15)] = u;
        }
    }
    __syncthreads();

    const int nl8 = tid >> 7;                  // 0..7 n-lane
    const int b4  = (tid >> 5) & 3;            // batch within group
    const int j   = tid & 31;                  // capsule

    float u4[16];
    if constexpr (T > 0) {
#pragma unroll
        for (int l = 0; l < 16; ++l) u4[l] = u_lds[b4 * 544 + j * 17 + l];
    }

    float acc[16];
#pragma unroll
    for (int l = 0; l < 16; ++l) acc[l] = 0.f;

    const float* wbase = Ws + (size_t)nb * 512 + j * 16;
    const float* xbase = xs_lds + b4 * NSL;

    for (int tile = 0; tile < NT; ++tile) {
        const int nl = tile * 8 + nl8;
        const float4* wr = (const float4*)(wbase + (size_t)nl * 512);
        float4 w0 = wr[0], w1 = wr[1], w2 = wr[2], w3 = wr[3];
        const float xsv = xbase[nl];
        float wgt;
        if constexpr (T == 0) {
            wgt = xsv * (1.f / 32.f);
        } else {
            float lg = w0.x*u4[0]  + w0.y*u4[1]  + w0.z*u4[2]  + w0.w*u4[3]
                     + w1.x*u4[4]  + w1.y*u4[5]  + w1.z*u4[6]  + w1.w*u4[7]
                     + w2.x*u4[8]  + w2.y*u4[9]  + w2.z*u4[10] + w2.w*u4[11]
                     + w3.x*u4[12] + w3.y*u4[13] + w3.z*u4[14] + w3.w*u4[15];
            lg *= xsv;
            float e = __expf(lg);              // |lg| < ~25: no max-pass needed
            float ss = e;
#pragma unroll
            for (int off = 1; off <= 16; off <<= 1) ss += __shfl_xor(ss, off);
            wgt = (e / ss) * xsv;
        }
        acc[0]  += wgt*w0.x; acc[1]  += wgt*w0.y; acc[2]  += wgt*w0.z; acc[3]  += wgt*w0.w;
        acc[4]  += wgt*w1.x; acc[5]  += wgt*w1.y; acc[6]  += wgt*w1.z; acc[7]  += wgt*w1.w;
        acc[8]  += wgt*w2.x; acc[9]  += wgt*w2.y; acc[10] += wgt*w2.z; acc[11] += wgt*w2.w;
        acc[12] += wgt*w3.x; acc[13] += wgt*w3.y; acc[14] += wgt*w3.z; acc[15] += wgt*w3.w;
    }

    // ---- two-stage n-lane reduction (upper half stores, lower half adds) ----
    if (nl8 >= 4) {
        float* sr = sred + (size_t)(tid - 512) * STR;
        ((float4*)sr)[0] = make_float4(acc[0],  acc[1],  acc[2],  acc[3]);
        ((float4*)sr)[1] = make_float4(acc[4],  acc[5],  acc[6],  acc[7]);
        ((float4*)sr)[2] = make_float4(acc[8],  acc[9],  acc[10], acc[11]);
        ((float4*)sr)[3] = make_float4(acc[12], acc[13], acc[14], acc[15]);
    }
    __syncthreads();
    if (nl8 < 4) {
        float* sr = sred + (size_t)tid * STR;
#pragma unroll
        for (int d = 0; d < 4; ++d) {
            float4 t = ((float4*)sr)[d];
            t.x += acc[d*4+0]; t.y += acc[d*4+1]; t.z += acc[d*4+2]; t.w += acc[d*4+3];
            ((float4*)sr)[d] = t;
        }
    }
    __syncthreads();

    // ---- tail: reduce 4 slots, write partial slice (coalesced, exclusive) ----
    for (int q = tid; q < BG * 512; q += NTHR) {
        const int ob = q >> 9, jl = q & 511;
        const int oj = jl >> 4, ol = jl & 15;
        float s = 0.f;
#pragma unroll
        for (int nl = 0; nl < 4; ++nl)
            s += sred[(size_t)(nl * 128 + ob * 32 + oj) * STR + ol];
        pout[((size_t)(bb + ob) * NSPL + sp) * 512 + jl] = s;
    }
}

// ---- final squash: out[b][j][l] = squash(sum_sp p2) ----
__global__ __launch_bounds__(512) void final_kernel(const float* __restrict__ p2,
                                                    float* __restrict__ out) {
    const int g = blockIdx.x * 512 + threadIdx.x;   // b*512 + jl
    const int b = g >> 9, jl = g & 511;
    const float* pp = p2 + ((size_t)b * NSPL) * 512 + jl;
    float s = 0.f;
#pragma unroll
    for (int s2 = 0; s2 < NSPL; ++s2) s += pp[s2 * 512];
    float sq = s * s;
#pragma unroll
    for (int off = 1; off <= 8; off <<= 1) sq += __shfl_xor(sq, off);
    out[g] = s * (sq / (1.f + sq) / sqrtf(sq + EPS_));
}

extern "C" void kernel_launch(void* const* d_in, const int* in_sizes, int n_in,
                              void* d_out, int out_size, void* d_ws, size_t ws_size,
                              hipStream_t stream) {
    const float* x = (const float*)d_in[0];   // [B, N, 8]
    const float* W = (const float*)d_in[1];   // [N, J, 8, L]
    float* out = (float*)d_out;               // [B, J, L]

    float* Ws  = (float*)d_ws;                         // N*J*L
    float* xsg = Ws  + (size_t)N_ * J_ * L_;           // B*N
    float* p0  = xsg + (size_t)B_ * N_;                // B*NSPL*512
    float* p1  = p0  + (size_t)B_ * NSPL * 512;        // B*NSPL*512
    float* p2  = p1  + (size_t)B_ * NSPL * 512;        // B*NSPL*512
    float* s0  = p2  + (size_t)B_ * NSPL * 512;        // B*512

    prep_kernel<<<1728, 256, 0, stream>>>(x, W, Ws, xsg);
    iter_kernel<0><<<NGRID, NTHR, 0, stream>>>(Ws, xsg, nullptr, nullptr, p0);
    iter_kernel<1><<<NGRID, NTHR, 0, stream>>>(Ws, xsg, p0, s0, p1);
    iter_kernel<2><<<NGRID, NTHR, 0, stream>>>(Ws, xsg, p1, s0, p2);
    final_kernel<<<64, 512, 0, stream>>>(p2, out);
}